// Round 12
// baseline (406.344 us; speedup 1.0000x reference)
//
#include <hip/hip_runtime.h>

#define NNODE 4096
#define NPB   1024

typedef float v2f __attribute__((ext_vector_type(2)));
typedef float v4f __attribute__((ext_vector_type(4)));

__device__ __forceinline__ float siluf(float x){ return x / (1.0f + expf(-x)); }

// v_pk_fma_f32 helpers: 2 f32 FMAs per instruction (VOP3P).
__device__ __forceinline__ v2f pk_fma_lo(v2f a, v2f b, v2f c){
  v2f d;
  asm("v_pk_fma_f32 %0, %1, %2, %3 op_sel_hi:[1,0,1]" : "=v"(d) : "v"(a), "v"(b), "v"(c));
  return d;
}
__device__ __forceinline__ v2f pk_fma_hi(v2f a, v2f b, v2f c){
  v2f d;
  asm("v_pk_fma_f32 %0, %1, %2, %3 op_sel:[0,1,0] op_sel_hi:[1,1,1]" : "=v"(d) : "v"(a), "v"(b), "v"(c));
  return d;
}
__device__ __forceinline__ v2f pk_fma2(v2f a, v2f b, v2f c){
  v2f d;
  asm("v_pk_fma_f32 %0, %1, %2, %3" : "=v"(d) : "v"(a), "v"(b), "v"(c));
  return d;
}
// SGPR-broadcast pk_fma: src1 is an sgpr pair; op_sel_hi[1]=0 -> both result
// halves read src1.lo, so the hi register (zext garbage/zero) is never used.
__device__ __forceinline__ v2f pk_fma_sb(v2f a, unsigned long long b, v2f c){
  v2f d;
  asm("v_pk_fma_f32 %0, %1, %2, %3 op_sel_hi:[1,0,1]" : "=v"(d) : "v"(a), "s"(b), "v"(c));
  return d;
}
// readlane -> zext to u64 (lo = value, hi = 0)
__device__ __forceinline__ unsigned long long rlz(float v, int ln){
  return (unsigned long long)(unsigned int)__builtin_amdgcn_readlane(__float_as_int(v), ln);
}
#define SHLO(h) __builtin_shufflevector((h), (h), 0, 1)
#define SHHI(h) __builtin_shufflevector((h), (h), 2, 3)

// ---------- K0: film = mish(cond) @ Wfilm + bfilm -> d_ws (4 x 2304 f32) ----------
__global__ __launch_bounds__(256) void k_film(const float* __restrict__ cond,
                                              const float* __restrict__ Wfilm,
                                              const float* __restrict__ bfilm,
                                              float* __restrict__ filmG){
  __shared__ float mL[256];
  int b = blockIdx.y;
  int t = threadIdx.x;
  int j = blockIdx.x*256 + t;
  float x = cond[b*256 + t];
  float sp = fmaxf(x, 0.f) + log1pf(expf(-fabsf(x)));
  mL[t] = x * tanhf(sp);
  __syncthreads();
  if(j >= 2304) return;
  float acc = bfilm[j];
  for(int i=0;i<256;i++) acc += mL[i] * Wfilm[i*2304 + j];
  filmG[b*2304 + j] = acc;
}

// ---------- K1: per-node precompute, wave-per-node, emb STAGED in LDS ----------
__global__ __launch_bounds__(256) void k_pre(const float* __restrict__ emb,
                                             const float* __restrict__ Wv,
                                             const float* __restrict__ Wsrc,
                                             const float* __restrict__ Wdst,
                                             float* __restrict__ ZG,
                                             float* __restrict__ QsG,
                                             float* __restrict__ QdG){
  __shared__ __align__(16) float S[4*1152];
  const int t = threadIdx.x;
  const int rg = __builtin_amdgcn_readfirstlane(t >> 6);
  const int lane = t & 63;
  const int c0 = lane*2;
  const int n0 = blockIdx.x*4;
  const int n = n0 + rg;

  // stage 4 nodes' emb tiles, coalesced
  {
    const float4* src = (const float4*)(emb + (size_t)n0*1152);
    float4* dst = (float4*)S;
    for(int i=t; i<1152; i+=256) dst[i] = src[i];
  }
  __syncthreads();
  const float* en = &S[rg*1152];   // wave-private LDS tile (broadcast reads)

  v2f z[9];
  #pragma unroll
  for(int l=0;l<9;l++) z[l] = (v2f)0.0f;
  for(int c4=0;c4<32;c4++){
    v2f wv0 = *(const v2f*)&Wv[(c4*4+0)*128 + c0];
    v2f wv1 = *(const v2f*)&Wv[(c4*4+1)*128 + c0];
    v2f wv2 = *(const v2f*)&Wv[(c4*4+2)*128 + c0];
    v2f wv3 = *(const v2f*)&Wv[(c4*4+3)*128 + c0];
    #pragma unroll
    for(int l=0;l<9;l++){
      v4f x4 = *(const v4f*)&en[l*128 + c4*4];   // LDS broadcast
      v2f h01 = SHLO(x4), h23 = SHHI(x4);
      z[l] = pk_fma_lo(wv0, h01, z[l]);
      z[l] = pk_fma_hi(wv1, h01, z[l]);
      z[l] = pk_fma_lo(wv2, h23, z[l]);
      z[l] = pk_fma_hi(wv3, h23, z[l]);
    }
  }
  #pragma unroll
  for(int l=0;l<9;l++) *(v2f*)&ZG[(size_t)n*1152 + l*128 + c0] = z[l];

  float qs = 0.f, qd = 0.f;
  for(int c4=0;c4<32;c4++){
    v4f e4 = *(const v4f*)&en[c4*4];             // LDS broadcast
    qs = fmaf(e4.x, Wsrc[(c4*4+0)*64 + lane], qs);
    qs = fmaf(e4.y, Wsrc[(c4*4+1)*64 + lane], qs);
    qs = fmaf(e4.z, Wsrc[(c4*4+2)*64 + lane], qs);
    qs = fmaf(e4.w, Wsrc[(c4*4+3)*64 + lane], qs);
    qd = fmaf(e4.x, Wdst[(c4*4+0)*64 + lane], qd);
    qd = fmaf(e4.y, Wdst[(c4*4+1)*64 + lane], qd);
    qd = fmaf(e4.z, Wdst[(c4*4+2)*64 + lane], qd);
    qd = fmaf(e4.w, Wdst[(c4*4+3)*64 + lane], qd);
  }
  QsG[n*64 + lane] = qs;
  QdG[n*64 + lane] = qd;
}

// -------- K2: FUSED edge+FFN kernel — wave-per-node, 2 nodes / 128-thread block --
// Edge phase LDS pool: HD 0..2048 | RB 2048..2304 | AT 2304..2432 | smalls.
// FFN phase is now LDS-FREE: activations stay in registers; wave-uniform
// broadcasts go v_readlane -> SGPR -> v_pk_fma_f32 (VALU pipe, per-SIMD)
// instead of ds_read_b128 broadcasts (DS pipe, shared per-CU — was ~66% of
// k_node's cycles at R11's 243us).
#define E2_HD   0
#define E2_RB   2048
#define E2_AT   2304
#define E2_KI   2432
#define E2_LEN  2448
#define E2_VL   2464
#define E2_W0   2480
#define E2_NPF  2560
__global__ __launch_bounds__(128, 4) void k_node(
    const float* __restrict__ coord,
    const float* __restrict__ emb,
    const float* __restrict__ We1, const float* __restrict__ be1,
    const float* __restrict__ We2, const float* __restrict__ be2,
    const float* __restrict__ wa,
    const float* __restrict__ Wo,
    const float* __restrict__ g1, const float* __restrict__ g2,
    const float* __restrict__ Wg, const float* __restrict__ Wf1,
    const float* __restrict__ Wf2,
    const float* __restrict__ Qs, const float* __restrict__ Qd,
    const float* __restrict__ Z,
    const float* __restrict__ filmG,
    float* __restrict__ out){
  __shared__ __align__(16) float S[2*E2_NPF];
  int* Si = (int*)S;
  const int t = threadIdx.x;
  const int w = __builtin_amdgcn_readfirstlane(t >> 6);
  const int lane = t & 63;
  const int bid = blockIdx.x;
  const int sbid = (bid & 7) * (NNODE/16) + (bid >> 3);   // XCD swizzle, bijective
  const int n = sbid*2 + w;
  const int base = n & ~(NPB - 1);
  const int self = n - base;
  const int NP = w * E2_NPF;
  const int c0 = lane*2;
  const int myh = lane >> 3;

  // ---- KNN ----
  {
    const float* cb = coord + (size_t)base*3;
    const float cx = cb[self*3+0];
    const float cy = cb[self*3+1];
    const float cz = cb[self*3+2];
    float d2a[16]; int ida[16];
    #pragma unroll
    for(int q=0;q<16;q++){
      int j = lane + q*64;
      float dx = __fsub_rn(cb[j*3+0], cx);
      float dy = __fsub_rn(cb[j*3+1], cy);
      float dz = __fsub_rn(cb[j*3+2], cz);
      float d2 = __fadd_rn(__fadd_rn(__fmul_rn(dx,dx), __fmul_rn(dy,dy)), __fmul_rn(dz,dz));
      if(j == self) d2 = 3e38f;
      d2a[q] = d2; ida[q] = j;
    }
    #pragma unroll 1
    for(int r=0;r<16;r++){
      float bd = d2a[0]; int bi = ida[0];
      #pragma unroll
      for(int q=1;q<16;q++){
        bool bet = (d2a[q] < bd) || (d2a[q] == bd && ida[q] < bi);
        if(bet){ bd = d2a[q]; bi = ida[q]; }
      }
      #pragma unroll
      for(int s=1;s<64;s<<=1){
        float od = __shfl_xor(bd, s, 64);
        int   oi = __shfl_xor(bi, s, 64);
        bool bet = (od < bd) || (od == bd && oi < bi);
        if(bet){ bd = od; bi = oi; }
      }
      if(lane == 0){
        Si[NP + E2_KI + r] = bi;
        float len = __fsqrt_rn(bd);
        S[NP + E2_LEN + r] = len;
        S[NP + E2_VL + r]  = (len <= 3.0f) ? 1.0f : 0.0f;
        int i0 = (int)(len * (127.0f/3.0f) + 0.5f);
        int w0 = i0 - 7;
        w0 = w0 < 0 ? 0 : (w0 > 112 ? 112 : w0);
        Si[NP + E2_W0 + r] = w0;
      }
      #pragma unroll
      for(int q=0;q<16;q++) if(ida[q] == bi) d2a[q] = 3e38f;
    }
  }
  __syncthreads();

  // ---- logits + in-wave softmax + windowed rbf ----
  {
    const int e0 = lane >> 3, hh = lane & 7;
    float4 qda = *(const float4*)&Qd[(size_t)n*64 + hh*8];
    float4 qdb = *(const float4*)&Qd[(size_t)n*64 + hh*8 + 4];
    float4 waa = *(const float4*)&wa[hh*8];
    float4 wab = *(const float4*)&wa[hh*8 + 4];
    float lg[2];
    #pragma unroll
    for(int s=0;s<2;s++){
      int e = e0 + s*8;
      int src = base + Si[NP + E2_KI + e];
      float4 qa = *(const float4*)&Qs[(size_t)src*64 + hh*8];
      float4 qb = *(const float4*)&Qs[(size_t)src*64 + hh*8 + 4];
      float sv = siluf(qda.x+qa.x)*waa.x + siluf(qda.y+qa.y)*waa.y
               + siluf(qda.z+qa.z)*waa.z + siluf(qda.w+qa.w)*waa.w
               + siluf(qdb.x+qb.x)*wab.x + siluf(qdb.y+qb.y)*wab.y
               + siluf(qdb.z+qb.z)*wab.z + siluf(qdb.w+qb.w)*wab.w;
      lg[s] = (S[NP + E2_VL + e] > 0.5f) ? sv : -1e9f;
    }
    float m = fmaxf(lg[0], lg[1]);
    m = fmaxf(m, __shfl_xor(m, 8, 64));
    m = fmaxf(m, __shfl_xor(m, 16, 64));
    m = fmaxf(m, __shfl_xor(m, 32, 64));
    float ex0 = expf(lg[0] - m), ex1 = expf(lg[1] - m);
    float den = ex0 + ex1;
    den += __shfl_xor(den, 8, 64);
    den += __shfl_xor(den, 16, 64);
    den += __shfl_xor(den, 32, 64);
    float inv = 1.0f/(den + 1e-9f);
    S[NP + E2_AT + lane]      = ex0*inv;
    S[NP + E2_AT + 64 + lane] = ex1*inv;

    const float step = 3.0f/127.0f;
    const float sigma = 3.0f/128.0f;
    #pragma unroll
    for(int k=0;k<4;k++){
      int idx = lane + k*64;
      int e = idx >> 4, wi = idx & 15;
      float len = S[NP + E2_LEN + e];
      int bin = Si[NP + E2_W0 + e] + wi;
      float d = (len - step*(float)bin) / sigma;
      S[NP + E2_RB + idx] = expf(-0.5f*d*d);
    }
  }
  __syncthreads();

  // ---- P4: hid = silu(rbf @ We1 + b1), all 16 edges, lane owns col pair ----
  {
    float a4[16][2]; int b0e[16];
    #pragma unroll
    for(int e=0;e<16;e++){ a4[e][0]=0.f; a4[e][1]=0.f; b0e[e] = Si[NP + E2_W0 + e]; }
    #pragma unroll 1
    for(int wi=0; wi<16; wi++){
      #pragma unroll
      for(int e=0;e<16;e++){
        float rb = S[NP + E2_RB + e*16 + wi];
        float2 we = *(const float2*)&We1[(size_t)(b0e[e] + wi)*128 + c0];
        a4[e][0] = fmaf(rb, we.x, a4[e][0]);
        a4[e][1] = fmaf(rb, we.y, a4[e][1]);
      }
    }
    float2 b1v = *(const float2*)&be1[c0];
    #pragma unroll
    for(int e=0;e<16;e++){
      float2 o; o.x = siluf(a4[e][0] + b1v.x); o.y = siluf(a4[e][1] + b1v.y);
      *(float2*)&S[NP + E2_HD + e*128 + c0] = o;
    }
  }
  __syncthreads();

  // ---- P5: eh = hid @ We2 + b2 — registers (lane-local cols) ----
  v2f a5[16];
  #pragma unroll
  for(int e=0;e<16;e++) a5[e] = (v2f)0.0f;
  #pragma unroll 1
  for(int c4=0;c4<32;c4++){
    v2f w0 = *(const v2f*)&We2[(c4*4+0)*128 + c0];
    v2f w1 = *(const v2f*)&We2[(c4*4+1)*128 + c0];
    v2f w2 = *(const v2f*)&We2[(c4*4+2)*128 + c0];
    v2f w3 = *(const v2f*)&We2[(c4*4+3)*128 + c0];
    #pragma unroll
    for(int e=0;e<16;e++){
      v4f h4 = *(const v4f*)&S[NP + E2_HD + e*128 + c4*4];
      v2f h01 = SHLO(h4), h23 = SHHI(h4);
      a5[e] = pk_fma_lo(w0, h01, a5[e]);
      a5[e] = pk_fma_hi(w1, h01, a5[e]);
      a5[e] = pk_fma_lo(w2, h23, a5[e]);
      a5[e] = pk_fma_hi(w3, h23, a5[e]);
    }
  }

  // ---- P6: agg -> REGISTERS (no LDS write) ----
  v2f ag[9];
  {
    v2f b2v = *(const v2f*)&be2[c0];
    #pragma unroll
    for(int l=0;l<9;l++) ag[l] = (v2f)0.0f;
    #pragma unroll 4
    for(int e=0;e<16;e++){
      int src = base + Si[NP + E2_KI + e];
      const float* zp = &Z[(size_t)src*1152 + c0];
      float at = S[NP + E2_AT + e*8 + myh];
      v2f sc = (a5[e] + b2v) * at;
      #pragma unroll
      for(int l=0;l<9;l++){
        v2f z2 = *(const v2f*)&zp[l*128];
        ag[l] = pk_fma2(z2, sc, ag[l]);
      }
    }
  }

  // ========== FFN phase: LDS-free, readlane-broadcast GEMMs ==========

  // GEMM1: x = ag @ Wo
  v2f x[9];
  #pragma unroll
  for(int l=0;l<9;l++) x[l] = (v2f)0.0f;
  #pragma unroll 1
  for(int c4=0;c4<32;c4++){
    int ln0 = c4*2, ln1 = ln0+1;
    v2f w0 = *(const v2f*)&Wo[(c4*4+0)*128 + c0];
    v2f w1 = *(const v2f*)&Wo[(c4*4+1)*128 + c0];
    v2f w2 = *(const v2f*)&Wo[(c4*4+2)*128 + c0];
    v2f w3 = *(const v2f*)&Wo[(c4*4+3)*128 + c0];
    #pragma unroll
    for(int l=0;l<9;l++){
      unsigned long long h0 = rlz(ag[l][0], ln0);
      unsigned long long h1 = rlz(ag[l][1], ln0);
      unsigned long long h2 = rlz(ag[l][0], ln1);
      unsigned long long h3 = rlz(ag[l][1], ln1);
      x[l] = pk_fma_sb(w0, h0, x[l]);
      x[l] = pk_fma_sb(w1, h1, x[l]);
      x[l] = pk_fma_sb(w2, h2, x[l]);
      x[l] = pk_fma_sb(w3, h3, x[l]);
    }
  }

  // += emb; rms (in-wave shfl); HL -> registers
  v2f hl[9];
  {
    float g2a = g2[c0], g2b = g2[c0+1];
    #pragma unroll
    for(int l=0;l<9;l++){
      v2f e2 = *(const v2f*)&emb[(size_t)n*1152 + l*128 + c0];
      x[l] += e2;
      float sq = x[l][0]*x[l][0] + x[l][1]*x[l][1];
      #pragma unroll
      for(int s=1;s<64;s<<=1) sq += __shfl_xor(sq, s, 64);
      float ss = sqrtf(sq/128.f + 1e-6f);
      hl[l][0] = x[l][0]/ss*g2a;
      hl[l][1] = x[l][1]/ss*g2b;
    }
  }

  // GEMM2+GEMM3: two sequential 128-col f-tile passes, all register-resident
  #pragma unroll 1
  for(int ft=0;ft<2;ft++){
    v2f ha[9]; v2f ga = (v2f)0.0f;
    #pragma unroll
    for(int l=0;l<9;l++) ha[l] = (v2f)0.0f;
    #pragma unroll 1
    for(int c4=0;c4<32;c4++){
      int ln0 = c4*2, ln1 = ln0+1;
      v2f wf0 = *(const v2f*)&Wf1[(c4*4+0)*256 + ft*128 + c0];
      v2f wf1 = *(const v2f*)&Wf1[(c4*4+1)*256 + ft*128 + c0];
      v2f wf2 = *(const v2f*)&Wf1[(c4*4+2)*256 + ft*128 + c0];
      v2f wf3 = *(const v2f*)&Wf1[(c4*4+3)*256 + ft*128 + c0];
      v2f wg0 = *(const v2f*)&Wg [(c4*4+0)*256 + ft*128 + c0];
      v2f wg1 = *(const v2f*)&Wg [(c4*4+1)*256 + ft*128 + c0];
      v2f wg2 = *(const v2f*)&Wg [(c4*4+2)*256 + ft*128 + c0];
      v2f wg3 = *(const v2f*)&Wg [(c4*4+3)*256 + ft*128 + c0];
      {
        unsigned long long h0 = rlz(hl[0][0], ln0);
        unsigned long long h1 = rlz(hl[0][1], ln0);
        unsigned long long h2 = rlz(hl[0][0], ln1);
        unsigned long long h3 = rlz(hl[0][1], ln1);
        ga = pk_fma_sb(wg0, h0, ga);
        ga = pk_fma_sb(wg1, h1, ga);
        ga = pk_fma_sb(wg2, h2, ga);
        ga = pk_fma_sb(wg3, h3, ga);
        ha[0] = pk_fma_sb(wf0, h0, ha[0]);
        ha[0] = pk_fma_sb(wf1, h1, ha[0]);
        ha[0] = pk_fma_sb(wf2, h2, ha[0]);
        ha[0] = pk_fma_sb(wf3, h3, ha[0]);
      }
      #pragma unroll
      for(int l=1;l<9;l++){
        unsigned long long h0 = rlz(hl[l][0], ln0);
        unsigned long long h1 = rlz(hl[l][1], ln0);
        unsigned long long h2 = rlz(hl[l][0], ln1);
        unsigned long long h3 = rlz(hl[l][1], ln1);
        ha[l] = pk_fma_sb(wf0, h0, ha[l]);
        ha[l] = pk_fma_sb(wf1, h1, ha[l]);
        ha[l] = pk_fma_sb(wf2, h2, ha[l]);
        ha[l] = pk_fma_sb(wf3, h3, ha[l]);
      }
    }
    float gx = siluf(ga[0]), gy = siluf(ga[1]);
    #pragma unroll
    for(int l=0;l<9;l++){ ha[l][0] *= gx; ha[l][1] *= gy; }
    #pragma unroll 1
    for(int f4=0;f4<32;f4++){
      int ln0 = f4*2, ln1 = ln0+1;
      v2f w0 = *(const v2f*)&Wf2[(ft*128 + f4*4+0)*128 + c0];
      v2f w1 = *(const v2f*)&Wf2[(ft*128 + f4*4+1)*128 + c0];
      v2f w2 = *(const v2f*)&Wf2[(ft*128 + f4*4+2)*128 + c0];
      v2f w3 = *(const v2f*)&Wf2[(ft*128 + f4*4+3)*128 + c0];
      #pragma unroll
      for(int l=0;l<9;l++){
        unsigned long long h0 = rlz(ha[l][0], ln0);
        unsigned long long h1 = rlz(ha[l][1], ln0);
        unsigned long long h2 = rlz(ha[l][0], ln1);
        unsigned long long h3 = rlz(ha[l][1], ln1);
        x[l] = pk_fma_sb(w0, h0, x[l]);
        x[l] = pk_fma_sb(w1, h1, x[l]);
        x[l] = pk_fma_sb(w2, h2, x[l]);
        x[l] = pk_fma_sb(w3, h3, x[l]);
      }
    }
  }

  // final rms (in-wave) + film + store
  {
    float g1a = g1[c0], g1b = g1[c0+1];
    int b = n >> 10;
    #pragma unroll
    for(int l=0;l<9;l++){
      float sq = x[l][0]*x[l][0] + x[l][1]*x[l][1];
      #pragma unroll
      for(int s=1;s<64;s<<=1) sq += __shfl_xor(sq, s, 64);
      float ss = sqrtf(sq/128.f + 1e-6f);
      v2f fw = *(const v2f*)&filmG[b*2304 + l*128 + c0];
      v2f fb = *(const v2f*)&filmG[b*2304 + 1152 + l*128 + c0];
      v2f o;
      o.x = x[l][0]/ss*g1a*fw.x + fb.x;
      o.y = x[l][1]/ss*g1b*fw.y + fb.y;
      *(v2f*)&out[12288 + (size_t)n*1152 + l*128 + c0] = o;
    }
  }
}

// ---------- K3: coords (exact f32 copy) + batch (= n>>10, f32) ----------
__global__ __launch_bounds__(256) void k_copy(const float* __restrict__ coord,
                                              float* __restrict__ out){
  int i = blockIdx.x*256 + threadIdx.x;
  if(i < 12288) out[i] = coord[i];
  int n = i - 12288;
  if(n >= 0 && n < 4096) out[12288 + 4718592 + n] = (float)(n >> 10);
}

extern "C" void kernel_launch(void* const* d_in, const int* in_sizes, int n_in,
                              void* d_out, int out_size, void* d_ws, size_t ws_size,
                              hipStream_t stream) {
  const float* coord = (const float*)d_in[0];
  const float* emb   = (const float*)d_in[1];
  const float* cond  = (const float*)d_in[3];
  const float* We1   = (const float*)d_in[4];
  const float* be1   = (const float*)d_in[5];
  const float* We2   = (const float*)d_in[6];
  const float* be2   = (const float*)d_in[7];
  const float* Wsrc  = (const float*)d_in[8];
  const float* Wdst  = (const float*)d_in[9];
  const float* wa    = (const float*)d_in[10];
  const float* Wv    = (const float*)d_in[11];
  const float* Wo    = (const float*)d_in[12];
  const float* g1    = (const float*)d_in[13];
  const float* g2    = (const float*)d_in[14];
  const float* Wg    = (const float*)d_in[15];
  const float* Wf1   = (const float*)d_in[16];
  const float* Wf2   = (const float*)d_in[17];
  const float* Wfilm = (const float*)d_in[18];
  const float* bfilm = (const float*)d_in[19];

  float* outf  = (float*)d_out;
  // workspace (floats): filmG 9216 | QsG 262144 | QdG 262144 | ZG 4718592 (~21 MB)
  float* filmG = (float*)d_ws;
  float* QsG   = filmG + 9216;
  float* QdG   = QsG + 262144;
  float* ZG    = QdG + 262144;

  k_film<<<dim3(9,4), 256, 0, stream>>>(cond, Wfilm, bfilm, filmG);
  k_pre<<<NNODE/4, 256, 0, stream>>>(emb, Wv, Wsrc, Wdst, ZG, QsG, QdG);
  k_node<<<NNODE/2, 128, 0, stream>>>(coord, emb,
                                      We1, be1, We2, be2, wa,
                                      Wo, g1, g2, Wg, Wf1, Wf2,
                                      QsG, QdG, ZG, filmG, outf);
  k_copy<<<64, 256, 0, stream>>>(coord, outf);
}

// Round 13
// 360.726 us; speedup vs baseline: 1.1265x; 1.1265x over previous
//
#include <hip/hip_runtime.h>

#define NNODE 4096
#define NPB   1024

typedef float v2f __attribute__((ext_vector_type(2)));
typedef float v4f __attribute__((ext_vector_type(4)));

__device__ __forceinline__ float siluf(float x){ return x / (1.0f + expf(-x)); }

// v_pk_fma_f32 helpers: 2 f32 FMAs per instruction (VOP3P).
__device__ __forceinline__ v2f pk_fma_lo(v2f a, v2f b, v2f c){
  v2f d;
  asm("v_pk_fma_f32 %0, %1, %2, %3 op_sel_hi:[1,0,1]" : "=v"(d) : "v"(a), "v"(b), "v"(c));
  return d;
}
__device__ __forceinline__ v2f pk_fma_hi(v2f a, v2f b, v2f c){
  v2f d;
  asm("v_pk_fma_f32 %0, %1, %2, %3 op_sel:[0,1,0] op_sel_hi:[1,1,1]" : "=v"(d) : "v"(a), "v"(b), "v"(c));
  return d;
}
__device__ __forceinline__ v2f pk_fma2(v2f a, v2f b, v2f c){
  v2f d;
  asm("v_pk_fma_f32 %0, %1, %2, %3" : "=v"(d) : "v"(a), "v"(b), "v"(c));
  return d;
}
#define SHLO(h) __builtin_shufflevector((h), (h), 0, 1)
#define SHHI(h) __builtin_shufflevector((h), (h), 2, 3)

// ---------- K0: film = mish(cond) @ Wfilm + bfilm -> d_ws (4 x 2304 f32) ----------
__global__ __launch_bounds__(256) void k_film(const float* __restrict__ cond,
                                              const float* __restrict__ Wfilm,
                                              const float* __restrict__ bfilm,
                                              float* __restrict__ filmG){
  __shared__ float mL[256];
  int b = blockIdx.y;
  int t = threadIdx.x;
  int j = blockIdx.x*256 + t;
  float x = cond[b*256 + t];
  float sp = fmaxf(x, 0.f) + log1pf(expf(-fabsf(x)));
  mL[t] = x * tanhf(sp);
  __syncthreads();
  if(j >= 2304) return;
  float acc = bfilm[j];
  for(int i=0;i<256;i++) acc += mL[i] * Wfilm[i*2304 + j];
  filmG[b*2304 + j] = acc;
}

// ---------- K1: per-node precompute, wave-per-node, emb STAGED in LDS ----------
__global__ __launch_bounds__(256) void k_pre(const float* __restrict__ emb,
                                             const float* __restrict__ Wv,
                                             const float* __restrict__ Wsrc,
                                             const float* __restrict__ Wdst,
                                             float* __restrict__ ZG,
                                             float* __restrict__ QsG,
                                             float* __restrict__ QdG){
  __shared__ __align__(16) float S[4*1152];
  const int t = threadIdx.x;
  const int rg = __builtin_amdgcn_readfirstlane(t >> 6);
  const int lane = t & 63;
  const int c0 = lane*2;
  const int n0 = blockIdx.x*4;
  const int n = n0 + rg;

  {
    const float4* src = (const float4*)(emb + (size_t)n0*1152);
    float4* dst = (float4*)S;
    for(int i=t; i<1152; i+=256) dst[i] = src[i];
  }
  __syncthreads();
  const float* en = &S[rg*1152];

  v2f z[9];
  #pragma unroll
  for(int l=0;l<9;l++) z[l] = (v2f)0.0f;
  for(int c4=0;c4<32;c4++){
    v2f wv0 = *(const v2f*)&Wv[(c4*4+0)*128 + c0];
    v2f wv1 = *(const v2f*)&Wv[(c4*4+1)*128 + c0];
    v2f wv2 = *(const v2f*)&Wv[(c4*4+2)*128 + c0];
    v2f wv3 = *(const v2f*)&Wv[(c4*4+3)*128 + c0];
    #pragma unroll
    for(int l=0;l<9;l++){
      v4f x4 = *(const v4f*)&en[l*128 + c4*4];
      v2f h01 = SHLO(x4), h23 = SHHI(x4);
      z[l] = pk_fma_lo(wv0, h01, z[l]);
      z[l] = pk_fma_hi(wv1, h01, z[l]);
      z[l] = pk_fma_lo(wv2, h23, z[l]);
      z[l] = pk_fma_hi(wv3, h23, z[l]);
    }
  }
  #pragma unroll
  for(int l=0;l<9;l++) *(v2f*)&ZG[(size_t)n*1152 + l*128 + c0] = z[l];

  float qs = 0.f, qd = 0.f;
  for(int c4=0;c4<32;c4++){
    v4f e4 = *(const v4f*)&en[c4*4];
    qs = fmaf(e4.x, Wsrc[(c4*4+0)*64 + lane], qs);
    qs = fmaf(e4.y, Wsrc[(c4*4+1)*64 + lane], qs);
    qs = fmaf(e4.z, Wsrc[(c4*4+2)*64 + lane], qs);
    qs = fmaf(e4.w, Wsrc[(c4*4+3)*64 + lane], qs);
    qd = fmaf(e4.x, Wdst[(c4*4+0)*64 + lane], qd);
    qd = fmaf(e4.y, Wdst[(c4*4+1)*64 + lane], qd);
    qd = fmaf(e4.z, Wdst[(c4*4+2)*64 + lane], qd);
    qd = fmaf(e4.w, Wdst[(c4*4+3)*64 + lane], qd);
  }
  QsG[n*64 + lane] = qs;
  QdG[n*64 + lane] = qd;
}

// -------- K2: FUSED edge+FFN kernel — wave-per-node, 2 nodes / 128-thread block --
// FFN back to R11 structure (LDS broadcast reads — R12's readlane was slower).
// NEW: software-pipelined weight prefetch (next c4's weight regs loaded before
// computing current c4) in P5/GEMM1/GEMM2/GEMM3 — the `unroll 1` loops exposed
// one L2 round-trip per iteration (R11 latency model). Also k_copy folded in.
#define E2_HD   0
#define E2_RB   2048
#define E2_AT   2304
#define E2_KI   2432
#define E2_LEN  2448
#define E2_VL   2464
#define E2_W0   2480
#define F_ACT   0
#define F_HID   1152
#define E2_NPF  2560
__global__ __launch_bounds__(128, 4) void k_node(
    const float* __restrict__ coord,
    const float* __restrict__ emb,
    const float* __restrict__ We1, const float* __restrict__ be1,
    const float* __restrict__ We2, const float* __restrict__ be2,
    const float* __restrict__ wa,
    const float* __restrict__ Wo,
    const float* __restrict__ g1, const float* __restrict__ g2,
    const float* __restrict__ Wg, const float* __restrict__ Wf1,
    const float* __restrict__ Wf2,
    const float* __restrict__ Qs, const float* __restrict__ Qd,
    const float* __restrict__ Z,
    const float* __restrict__ filmG,
    float* __restrict__ out){
  __shared__ __align__(16) float S[2*E2_NPF];
  int* Si = (int*)S;
  const int t = threadIdx.x;
  const int w = __builtin_amdgcn_readfirstlane(t >> 6);
  const int lane = t & 63;
  const int bid = blockIdx.x;
  const int sbid = (bid & 7) * (NNODE/16) + (bid >> 3);   // XCD swizzle, bijective
  const int n = sbid*2 + w;
  const int base = n & ~(NPB - 1);
  const int self = n - base;
  const int NP = w * E2_NPF;
  const int c0 = lane*2;
  const int myh = lane >> 3;

  // ---- KNN ----
  {
    const float* cb = coord + (size_t)base*3;
    const float cx = cb[self*3+0];
    const float cy = cb[self*3+1];
    const float cz = cb[self*3+2];
    float d2a[16]; int ida[16];
    #pragma unroll
    for(int q=0;q<16;q++){
      int j = lane + q*64;
      float dx = __fsub_rn(cb[j*3+0], cx);
      float dy = __fsub_rn(cb[j*3+1], cy);
      float dz = __fsub_rn(cb[j*3+2], cz);
      float d2 = __fadd_rn(__fadd_rn(__fmul_rn(dx,dx), __fmul_rn(dy,dy)), __fmul_rn(dz,dz));
      if(j == self) d2 = 3e38f;
      d2a[q] = d2; ida[q] = j;
    }
    #pragma unroll 1
    for(int r=0;r<16;r++){
      float bd = d2a[0]; int bi = ida[0];
      #pragma unroll
      for(int q=1;q<16;q++){
        bool bet = (d2a[q] < bd) || (d2a[q] == bd && ida[q] < bi);
        if(bet){ bd = d2a[q]; bi = ida[q]; }
      }
      #pragma unroll
      for(int s=1;s<64;s<<=1){
        float od = __shfl_xor(bd, s, 64);
        int   oi = __shfl_xor(bi, s, 64);
        bool bet = (od < bd) || (od == bd && oi < bi);
        if(bet){ bd = od; bi = oi; }
      }
      if(lane == 0){
        Si[NP + E2_KI + r] = bi;
        float len = __fsqrt_rn(bd);
        S[NP + E2_LEN + r] = len;
        S[NP + E2_VL + r]  = (len <= 3.0f) ? 1.0f : 0.0f;
        int i0 = (int)(len * (127.0f/3.0f) + 0.5f);
        int w0 = i0 - 7;
        w0 = w0 < 0 ? 0 : (w0 > 112 ? 112 : w0);
        Si[NP + E2_W0 + r] = w0;
      }
      #pragma unroll
      for(int q=0;q<16;q++) if(ida[q] == bi) d2a[q] = 3e38f;
    }
  }
  __syncthreads();

  // ---- logits + in-wave softmax + windowed rbf ----
  {
    const int e0 = lane >> 3, hh = lane & 7;
    float4 qda = *(const float4*)&Qd[(size_t)n*64 + hh*8];
    float4 qdb = *(const float4*)&Qd[(size_t)n*64 + hh*8 + 4];
    float4 waa = *(const float4*)&wa[hh*8];
    float4 wab = *(const float4*)&wa[hh*8 + 4];
    float lg[2];
    #pragma unroll
    for(int s=0;s<2;s++){
      int e = e0 + s*8;
      int src = base + Si[NP + E2_KI + e];
      float4 qa = *(const float4*)&Qs[(size_t)src*64 + hh*8];
      float4 qb = *(const float4*)&Qs[(size_t)src*64 + hh*8 + 4];
      float sv = siluf(qda.x+qa.x)*waa.x + siluf(qda.y+qa.y)*waa.y
               + siluf(qda.z+qa.z)*waa.z + siluf(qda.w+qa.w)*waa.w
               + siluf(qdb.x+qb.x)*wab.x + siluf(qdb.y+qb.y)*wab.y
               + siluf(qdb.z+qb.z)*wab.z + siluf(qdb.w+qb.w)*wab.w;
      lg[s] = (S[NP + E2_VL + e] > 0.5f) ? sv : -1e9f;
    }
    float m = fmaxf(lg[0], lg[1]);
    m = fmaxf(m, __shfl_xor(m, 8, 64));
    m = fmaxf(m, __shfl_xor(m, 16, 64));
    m = fmaxf(m, __shfl_xor(m, 32, 64));
    float ex0 = expf(lg[0] - m), ex1 = expf(lg[1] - m);
    float den = ex0 + ex1;
    den += __shfl_xor(den, 8, 64);
    den += __shfl_xor(den, 16, 64);
    den += __shfl_xor(den, 32, 64);
    float inv = 1.0f/(den + 1e-9f);
    S[NP + E2_AT + lane]      = ex0*inv;
    S[NP + E2_AT + 64 + lane] = ex1*inv;

    const float step = 3.0f/127.0f;
    const float sigma = 3.0f/128.0f;
    #pragma unroll
    for(int k=0;k<4;k++){
      int idx = lane + k*64;
      int e = idx >> 4, wi = idx & 15;
      float len = S[NP + E2_LEN + e];
      int bin = Si[NP + E2_W0 + e] + wi;
      float d = (len - step*(float)bin) / sigma;
      S[NP + E2_RB + idx] = expf(-0.5f*d*d);
    }
  }
  __syncthreads();

  // ---- P4: hid = silu(rbf @ We1 + b1) ----
  {
    float a4[16][2]; int b0e[16];
    #pragma unroll
    for(int e=0;e<16;e++){ a4[e][0]=0.f; a4[e][1]=0.f; b0e[e] = Si[NP + E2_W0 + e]; }
    #pragma unroll 1
    for(int wi=0; wi<16; wi++){
      #pragma unroll
      for(int e=0;e<16;e++){
        float rb = S[NP + E2_RB + e*16 + wi];
        float2 we = *(const float2*)&We1[(size_t)(b0e[e] + wi)*128 + c0];
        a4[e][0] = fmaf(rb, we.x, a4[e][0]);
        a4[e][1] = fmaf(rb, we.y, a4[e][1]);
      }
    }
    float2 b1v = *(const float2*)&be1[c0];
    #pragma unroll
    for(int e=0;e<16;e++){
      float2 o; o.x = siluf(a4[e][0] + b1v.x); o.y = siluf(a4[e][1] + b1v.y);
      *(float2*)&S[NP + E2_HD + e*128 + c0] = o;
    }
  }
  __syncthreads();

  // ---- P5: eh = hid @ We2 + b2 — registers; We2 stream software-pipelined ----
  v2f a5[16];
  #pragma unroll
  for(int e=0;e<16;e++) a5[e] = (v2f)0.0f;
  {
    const float* Wp = We2 + c0;
    v2f w0 = *(const v2f*)&Wp[0*128];
    v2f w1 = *(const v2f*)&Wp[1*128];
    v2f w2 = *(const v2f*)&Wp[2*128];
    v2f w3 = *(const v2f*)&Wp[3*128];
    #pragma unroll 1
    for(int c4=0;c4<32;c4++){
      int nc = c4 < 31 ? c4+1 : 31;
      v2f p0 = *(const v2f*)&Wp[(nc*4+0)*128];
      v2f p1 = *(const v2f*)&Wp[(nc*4+1)*128];
      v2f p2 = *(const v2f*)&Wp[(nc*4+2)*128];
      v2f p3 = *(const v2f*)&Wp[(nc*4+3)*128];
      #pragma unroll
      for(int e=0;e<16;e++){
        v4f h4 = *(const v4f*)&S[NP + E2_HD + e*128 + c4*4];
        v2f h01 = SHLO(h4), h23 = SHHI(h4);
        a5[e] = pk_fma_lo(w0, h01, a5[e]);
        a5[e] = pk_fma_hi(w1, h01, a5[e]);
        a5[e] = pk_fma_lo(w2, h23, a5[e]);
        a5[e] = pk_fma_hi(w3, h23, a5[e]);
      }
      w0=p0; w1=p1; w2=p2; w3=p3;
    }
  }

  // ---- P6: agg -> LDS ACT (wave-private, no barrier) ----
  {
    v2f b2v = *(const v2f*)&be2[c0];
    v2f ag[9];
    #pragma unroll
    for(int l=0;l<9;l++) ag[l] = (v2f)0.0f;
    #pragma unroll 4
    for(int e=0;e<16;e++){
      int src = base + Si[NP + E2_KI + e];
      const float* zp = &Z[(size_t)src*1152 + c0];
      float at = S[NP + E2_AT + e*8 + myh];
      v2f sc = (a5[e] + b2v) * at;
      #pragma unroll
      for(int l=0;l<9;l++){
        v2f z2 = *(const v2f*)&zp[l*128];
        ag[l] = pk_fma2(z2, sc, ag[l]);
      }
    }
    #pragma unroll
    for(int l=0;l<9;l++) *(v2f*)&S[NP + F_ACT + l*128 + c0] = ag[l];
  }

  // ================= FFN phase (LDS wave-private, zero barriers) =============
  float* W_ = &S[NP];

  // GEMM1: x = agg @ Wo — Wo stream software-pipelined
  v2f x[9];
  #pragma unroll
  for(int l=0;l<9;l++) x[l] = (v2f)0.0f;
  {
    const float* Wp = Wo + c0;
    v2f w0 = *(const v2f*)&Wp[0*128];
    v2f w1 = *(const v2f*)&Wp[1*128];
    v2f w2 = *(const v2f*)&Wp[2*128];
    v2f w3 = *(const v2f*)&Wp[3*128];
    #pragma unroll 1
    for(int c4=0;c4<32;c4++){
      int nc = c4 < 31 ? c4+1 : 31;
      v2f p0 = *(const v2f*)&Wp[(nc*4+0)*128];
      v2f p1 = *(const v2f*)&Wp[(nc*4+1)*128];
      v2f p2 = *(const v2f*)&Wp[(nc*4+2)*128];
      v2f p3 = *(const v2f*)&Wp[(nc*4+3)*128];
      #pragma unroll
      for(int l=0;l<9;l++){
        v4f a4 = *(const v4f*)&W_[F_ACT + l*128 + c4*4];
        v2f h01 = SHLO(a4), h23 = SHHI(a4);
        x[l] = pk_fma_lo(w0, h01, x[l]);
        x[l] = pk_fma_hi(w1, h01, x[l]);
        x[l] = pk_fma_lo(w2, h23, x[l]);
        x[l] = pk_fma_hi(w3, h23, x[l]);
      }
      w0=p0; w1=p1; w2=p2; w3=p3;
    }
  }

  // += emb; rms (in-wave shfl); HL -> ACT (overwrite)
  {
    float g2a = g2[c0], g2b = g2[c0+1];
    #pragma unroll
    for(int l=0;l<9;l++){
      v2f e2 = *(const v2f*)&emb[(size_t)n*1152 + l*128 + c0];
      x[l] += e2;
      float sq = x[l][0]*x[l][0] + x[l][1]*x[l][1];
      #pragma unroll
      for(int s=1;s<64;s<<=1) sq += __shfl_xor(sq, s, 64);
      float ss = sqrtf(sq/128.f + 1e-6f);
      v2f o; o.x = x[l][0]/ss*g2a; o.y = x[l][1]/ss*g2b;
      *(v2f*)&W_[F_ACT + l*128 + c0] = o;
    }
  }

  // GEMM2+GEMM3: two f-tile passes; Wf1/Wg and Wf2 streams software-pipelined
  #pragma unroll 1
  for(int ft=0;ft<2;ft++){
    v2f ha[9]; v2f ga = (v2f)0.0f;
    #pragma unroll
    for(int l=0;l<9;l++) ha[l] = (v2f)0.0f;
    {
      const float* Fp = Wf1 + ft*128 + c0;
      const float* Gp = Wg  + ft*128 + c0;
      v2f wf0 = *(const v2f*)&Fp[0*256];
      v2f wf1 = *(const v2f*)&Fp[1*256];
      v2f wf2 = *(const v2f*)&Fp[2*256];
      v2f wf3 = *(const v2f*)&Fp[3*256];
      v2f wg0 = *(const v2f*)&Gp[0*256];
      v2f wg1 = *(const v2f*)&Gp[1*256];
      v2f wg2 = *(const v2f*)&Gp[2*256];
      v2f wg3 = *(const v2f*)&Gp[3*256];
      #pragma unroll 1
      for(int c4=0;c4<32;c4++){
        int nc = c4 < 31 ? c4+1 : 31;
        v2f pf0 = *(const v2f*)&Fp[(nc*4+0)*256];
        v2f pf1 = *(const v2f*)&Fp[(nc*4+1)*256];
        v2f pf2 = *(const v2f*)&Fp[(nc*4+2)*256];
        v2f pf3 = *(const v2f*)&Fp[(nc*4+3)*256];
        v2f pg0 = *(const v2f*)&Gp[(nc*4+0)*256];
        v2f pg1 = *(const v2f*)&Gp[(nc*4+1)*256];
        v2f pg2 = *(const v2f*)&Gp[(nc*4+2)*256];
        v2f pg3 = *(const v2f*)&Gp[(nc*4+3)*256];
        v4f h0 = *(const v4f*)&W_[F_ACT + 0*128 + c4*4];
        v2f h01 = SHLO(h0), h23 = SHHI(h0);
        ga = pk_fma_lo(wg0, h01, ga);
        ga = pk_fma_hi(wg1, h01, ga);
        ga = pk_fma_lo(wg2, h23, ga);
        ga = pk_fma_hi(wg3, h23, ga);
        ha[0] = pk_fma_lo(wf0, h01, ha[0]);
        ha[0] = pk_fma_hi(wf1, h01, ha[0]);
        ha[0] = pk_fma_lo(wf2, h23, ha[0]);
        ha[0] = pk_fma_hi(wf3, h23, ha[0]);
        #pragma unroll
        for(int l=1;l<9;l++){
          v4f h4 = *(const v4f*)&W_[F_ACT + l*128 + c4*4];
          v2f a01 = SHLO(h4), a23 = SHHI(h4);
          ha[l] = pk_fma_lo(wf0, a01, ha[l]);
          ha[l] = pk_fma_hi(wf1, a01, ha[l]);
          ha[l] = pk_fma_lo(wf2, a23, ha[l]);
          ha[l] = pk_fma_hi(wf3, a23, ha[l]);
        }
        wf0=pf0; wf1=pf1; wf2=pf2; wf3=pf3;
        wg0=pg0; wg1=pg1; wg2=pg2; wg3=pg3;
      }
    }
    float gx = siluf(ga[0]), gy = siluf(ga[1]);
    #pragma unroll
    for(int l=0;l<9;l++){
      v2f o; o.x = ha[l][0]*gx; o.y = ha[l][1]*gy;
      *(v2f*)&W_[F_HID + l*128 + c0] = o;
    }
    {
      const float* Wp = Wf2 + (size_t)ft*128*128 + c0;
      v2f w0 = *(const v2f*)&Wp[0*128];
      v2f w1 = *(const v2f*)&Wp[1*128];
      v2f w2 = *(const v2f*)&Wp[2*128];
      v2f w3 = *(const v2f*)&Wp[3*128];
      #pragma unroll 1
      for(int f4=0;f4<32;f4++){
        int nf = f4 < 31 ? f4+1 : 31;
        v2f p0 = *(const v2f*)&Wp[(nf*4+0)*128];
        v2f p1 = *(const v2f*)&Wp[(nf*4+1)*128];
        v2f p2 = *(const v2f*)&Wp[(nf*4+2)*128];
        v2f p3 = *(const v2f*)&Wp[(nf*4+3)*128];
        #pragma unroll
        for(int l=0;l<9;l++){
          v4f h4 = *(const v4f*)&W_[F_HID + l*128 + f4*4];
          v2f h01 = SHLO(h4), h23 = SHHI(h4);
          x[l] = pk_fma_lo(w0, h01, x[l]);
          x[l] = pk_fma_hi(w1, h01, x[l]);
          x[l] = pk_fma_lo(w2, h23, x[l]);
          x[l] = pk_fma_hi(w3, h23, x[l]);
        }
        w0=p0; w1=p1; w2=p2; w3=p3;
      }
    }
  }

  // final rms (in-wave) + film + store
  {
    float g1a = g1[c0], g1b = g1[c0+1];
    int b = n >> 10;
    #pragma unroll
    for(int l=0;l<9;l++){
      float sq = x[l][0]*x[l][0] + x[l][1]*x[l][1];
      #pragma unroll
      for(int s=1;s<64;s<<=1) sq += __shfl_xor(sq, s, 64);
      float ss = sqrtf(sq/128.f + 1e-6f);
      v2f fw = *(const v2f*)&filmG[b*2304 + l*128 + c0];
      v2f fb = *(const v2f*)&filmG[b*2304 + 1152 + l*128 + c0];
      v2f o;
      o.x = x[l][0]/ss*g1a*fw.x + fb.x;
      o.y = x[l][1]/ss*g1b*fw.y + fb.y;
      *(v2f*)&out[12288 + (size_t)n*1152 + l*128 + c0] = o;
    }
  }

  // ---- folded k_copy: this wave's node writes its coords + batch ----
  if(lane < 3) out[(size_t)n*3 + lane] = coord[(size_t)n*3 + lane];
  if(lane == 3) out[12288 + 4718592 + n] = (float)(n >> 10);
}

extern "C" void kernel_launch(void* const* d_in, const int* in_sizes, int n_in,
                              void* d_out, int out_size, void* d_ws, size_t ws_size,
                              hipStream_t stream) {
  const float* coord = (const float*)d_in[0];
  const float* emb   = (const float*)d_in[1];
  const float* cond  = (const float*)d_in[3];
  const float* We1   = (const float*)d_in[4];
  const float* be1   = (const float*)d_in[5];
  const float* We2   = (const float*)d_in[6];
  const float* be2   = (const float*)d_in[7];
  const float* Wsrc  = (const float*)d_in[8];
  const float* Wdst  = (const float*)d_in[9];
  const float* wa    = (const float*)d_in[10];
  const float* Wv    = (const float*)d_in[11];
  const float* Wo    = (const float*)d_in[12];
  const float* g1    = (const float*)d_in[13];
  const float* g2    = (const float*)d_in[14];
  const float* Wg    = (const float*)d_in[15];
  const float* Wf1   = (const float*)d_in[16];
  const float* Wf2   = (const float*)d_in[17];
  const float* Wfilm = (const float*)d_in[18];
  const float* bfilm = (const float*)d_in[19];

  float* outf  = (float*)d_out;
  // workspace (floats): filmG 9216 | QsG 262144 | QdG 262144 | ZG 4718592 (~21 MB)
  float* filmG = (float*)d_ws;
  float* QsG   = filmG + 9216;
  float* QdG   = QsG + 262144;
  float* ZG    = QdG + 262144;

  k_film<<<dim3(9,4), 256, 0, stream>>>(cond, Wfilm, bfilm, filmG);
  k_pre<<<NNODE/4, 256, 0, stream>>>(emb, Wv, Wsrc, Wdst, ZG, QsG, QdG);
  k_node<<<NNODE/2, 128, 0, stream>>>(coord, emb,
                                      We1, be1, We2, be2, wa,
                                      Wo, g1, g2, Wg, Wf1, Wf2,
                                      QsG, QdG, ZG, filmG, outf);
}